// Round 9
// baseline (79.763 us; speedup 1.0000x reference)
//
#include <hip/hip_runtime.h>
#include <hip/hip_bf16.h>

#define BB 512
#define TT 2048
#define SS 128
#define LL 64
#define PP (TT - LL + 1)   // 1985

// ws float-offset layout:
//   [0, 262144)       partials: part[j*65536 + b*128 + s], j = 0..3
//   [262144, 262272)  s2c[s] = sum(scent^2) + 64*mean^2  (raw sum of squares)
//   byte 1049600..    centered bf16 shapelets, padded rows: 128 x 72 shorts
#define WS_PART 0
#define WS_S2C  262144
#define WS_SHB_BYTE 1049600
#define SH_ROW_SHORTS 72          // 64 data + 8 pad (row stride 144 B)

#define SW    512                 // windows per strip
#define XF_N  624                 // staged fp32 elems per strip (zero-padded)
#define XCP_BUILD 152             // xcp words actually built (>= max used 150)
#define XCP_W 162                 // row stride in 8B words; (2*162)%32==4 ->
                                  // copies start 4 banks apart (bank-balanced)

typedef __attribute__((ext_vector_type(8))) short  short8;
typedef __attribute__((ext_vector_type(4))) float  float4v;

__device__ __forceinline__ unsigned f2bf1(float f) {
  union { float f; unsigned u; } v; v.f = f;
  return (v.u + 0x7FFFu + ((v.u >> 16) & 1u)) >> 16;   // RNE fp32->bf16
}

// ---------- prep: center shapelets, bf16-pack (padded rows), s2c ----------
__global__ __launch_bounds__(64)
void prep_kernel(const float* __restrict__ shg, float* __restrict__ ws) {
  const int s = blockIdx.x, l = threadIdx.x;
  float v = shg[s * LL + l];
  float sum = v;
  #pragma unroll
  for (int off = 1; off < 64; off <<= 1) sum += __shfl_xor(sum, off);
  const float mean = sum * (1.f / 64.f);
  const float sc = v - mean;
  float sq = sc * sc;
  #pragma unroll
  for (int off = 1; off < 64; off <<= 1) sq += __shfl_xor(sq, off);

  unsigned bfu = f2bf1(sc);
  unsigned other = __shfl_down(bfu, 1);
  if ((l & 1) == 0) {
    unsigned* shbw = (unsigned*)((char*)ws + WS_SHB_BYTE);
    shbw[s * (SH_ROW_SHORTS / 2) + (l >> 1)] = bfu | (other << 16);
  }
  if (l == 0) ws[WS_S2C + s] = sq + 64.f * mean * mean;
}

// ---------- main: 4 strips/sample, 256 thr (4 waves), ~16 KB LDS ----------
// wave w: shalf = w&1 (64 shapelets), phalf = w>>1 (256 windows, 8 tile-pairs).
// d2 = c0[p] + s2c[s] - 2*cross(x, scent); C-init = -c0/2; g = max(cross - c0/2).
// Rolling ring + 1-iter prefetch: 2 new A ds_read_b128 per 32 windows.
__global__ __launch_bounds__(256)
void shapelet_main(const float* __restrict__ x, float* ws) {
  __shared__ __align__(16) float xf[XF_N];
  __shared__ __align__(16) unsigned long long xcp[8][XCP_W];
  __shared__ float c0h[544];
  __shared__ float wred[4 * 64];

  const int t = threadIdx.x;
  const int bid = blockIdx.x;
  const int b = bid >> 2, j = bid & 3;
  const int pg = j * SW;

  const int lane = t & 63, wave = t >> 6;
  const int n = lane & 15, q = lane >> 4;
  const int shalf = wave & 1, phalf = wave >> 1;

  // ---- B fragments from global (L2-resident; latency hides under staging) ----
  short8 bf[2][4];
  {
    const short* shb = (const short*)((const char*)ws + WS_SHB_BYTE);
    #pragma unroll
    for (int st = 0; st < 4; ++st) {
      const int row = shalf * 64 + st * 16 + n;
      bf[0][st] = *(const short8*)(shb + row * SH_ROW_SHORTS + q * 8);
      bf[1][st] = *(const short8*)(shb + row * SH_ROW_SHORTS + 32 + q * 8);
    }
  }

  // ---- stage x strip [pg, pg+XF_N) into LDS, zero-pad past TT ----
  if (t < XF_N / 4) {
    const int g0 = pg + 4 * t;
    float4v v = {0.f, 0.f, 0.f, 0.f};
    if (g0 + 3 < TT) {
      v = *(const float4v*)(x + (size_t)b * TT + g0);
    } else if (g0 < TT) {
      #pragma unroll
      for (int k = 0; k < 4; ++k) v[k] = (g0 + k < TT) ? x[(size_t)b * TT + g0 + k] : 0.f;
    }
    *(float4v*)(xf + 4 * t) = v;
  }

  __syncthreads();

  if (wave < 2) {
    // ---- window stats (threads 0..127): windows 4t..4t+3 ----
    const float4v* xf4 = (const float4v*)xf;
    float S = 0.f, Q = 0.f;
    float4v v0 = xf4[t];
    {
      float4v v = v0;
      #pragma unroll
      for (int ch = 0; ch < 16; ++ch) {
        S += (v[0] + v[1]) + (v[2] + v[3]);
        Q = fmaf(v[0], v[0], Q); Q = fmaf(v[1], v[1], Q);
        Q = fmaf(v[2], v[2], Q); Q = fmaf(v[3], v[3], Q);
        if (ch < 15) v = xf4[t + ch + 1];
      }
    }
    float4v vN = xf4[t + 16];
    const int p0s = 4 * t;
    #pragma unroll
    for (int r = 0; r < 4; ++r) {
      const bool valid = (pg + p0s + r) < PP;
      const float c0 = Q - S * S * (1.f / 64.f);
      c0h[p0s + r] = valid ? (-0.5f * c0) : -INFINITY;
      if (r < 3) {
        const float vin = vN[r], vout = v0[r];
        S += vin - vout;
        Q += fmaf(vin, vin, -vout * vout);
      }
    }
  } else {
    // ---- copy-build (threads 128..255): 8 shifted bf16 copies ----
    // FIX vs R8: strided loop so words 128..151 are built too.
    for (int w = t - 128; w < XCP_BUILD; w += 128) {
      const float4v* xf4 = (const float4v*)xf;
      float4v A = xf4[w], Bv = xf4[w + 1], Cv = xf4[w + 2];
      unsigned bfx[11];
      #pragma unroll
      for (int k = 0; k < 4; ++k) bfx[k] = f2bf1(A[k]);
      #pragma unroll
      for (int k = 0; k < 4; ++k) bfx[4 + k] = f2bf1(Bv[k]);
      #pragma unroll
      for (int k = 0; k < 3; ++k) bfx[8 + k] = f2bf1(Cv[k]);
      #pragma unroll
      for (int c = 0; c < 8; ++c) {
        unsigned long long pk =
            (unsigned long long)bfx[c] |
            ((unsigned long long)bfx[c + 1] << 16) |
            ((unsigned long long)bfx[c + 2] << 32) |
            ((unsigned long long)bfx[c + 3] << 48);
        xcp[c][w] = pk;
      }
    }
  }

  // pad c0h tail (prefetch reads up to c0h[543]; keep finite/poisoned)
  if (t < 32) c0h[SW + t] = -INFINITY;

  __syncthreads();

  // ---- main MFMA loop: ring + 1-iter prefetch, 8 iters of 32 windows ----
  const int cc = n & 7;
  const int lw = 2 * q + 2 * (n >> 3);          // even => aligned ds_read_b128
  const unsigned long long* xc = &xcp[cc][0];
  const int base = phalf * 256;
  const int w0 = (base >> 2) + lw;

  float rmax[4];
  #pragma unroll
  for (int st = 0; st < 4; ++st) rmax[st] = -INFINITY;

  short8 h0 = *(const short8*)&xc[w0];           // frag(base,    kb0)
  short8 h1 = *(const short8*)&xc[w0 + 4];       // frag(base+16, kb0)
  short8 l0 = *(const short8*)&xc[w0 + 8];       // frag(base,    kb1)
  short8 l1 = *(const short8*)&xc[w0 + 12];      // frag(base+16, kb1)
  float4v c0A = *(const float4v*)&c0h[base + 4 * q];
  float4v c0B = *(const float4v*)&c0h[base + 16 + 4 * q];

  for (int mt2 = 0; mt2 < 8; ++mt2) {
    // prefetch next iter (reads stay within built xcp/c0h; last-iter unused)
    const int wbn = w0 + 8 * ((mt2 + 1) & 7);
    const short8 nl0 = *(const short8*)&xc[wbn + 8];
    const short8 nl1 = *(const short8*)&xc[wbn + 12];
    const int pAn = base + 32 * (mt2 + 1) + 4 * q;
    const float4v nc0A = *(const float4v*)&c0h[pAn];
    const float4v nc0B = *(const float4v*)&c0h[pAn + 16];

    #pragma unroll
    for (int st = 0; st < 4; ++st) {
      float4v accA = __builtin_amdgcn_mfma_f32_16x16x32_bf16(h0, bf[0][st], c0A, 0, 0, 0);
      float4v accB = __builtin_amdgcn_mfma_f32_16x16x32_bf16(h1, bf[0][st], c0B, 0, 0, 0);
      accA = __builtin_amdgcn_mfma_f32_16x16x32_bf16(l0, bf[1][st], accA, 0, 0, 0);
      accB = __builtin_amdgcn_mfma_f32_16x16x32_bf16(l1, bf[1][st], accB, 0, 0, 0);
      const float mA = fmaxf(fmaxf(accA[0], accA[1]), fmaxf(accA[2], accA[3]));
      const float mB = fmaxf(fmaxf(accB[0], accB[1]), fmaxf(accB[2], accB[3]));
      rmax[st] = fmaxf(rmax[st], fmaxf(mA, mB));
    }
    h0 = l0; h1 = l1;                            // frag(p,kb1) == frag(p+32,kb0)
    l0 = nl0; l1 = nl1;
    c0A = nc0A; c0B = nc0B;
  }

  // ---- reduce: across q (shfl), across phalf waves (LDS), write partial ----
  #pragma unroll
  for (int st = 0; st < 4; ++st) {
    float v = rmax[st];
    v = fmaxf(v, __shfl_xor(v, 16));
    v = fmaxf(v, __shfl_xor(v, 32));
    if (q == 0) wred[wave * 64 + st * 16 + n] = v;
  }
  __syncthreads();

  if (t < SS) {
    const int g = t >> 6, k = t & 63;            // s = g*64 + k; waves {g, g+2}
    const float v = fmaxf(wred[g * 64 + k], wred[(g + 2) * 64 + k]);
    ws[WS_PART + (size_t)j * 65536 + (size_t)b * 128 + t] = v;
  }
}

// ---------- combine: max over 4 strips, d2 = s2c - 2g, sqrt ----------
__global__ __launch_bounds__(256)
void combine_kernel(const float* __restrict__ ws, float* __restrict__ out) {
  const int tid = blockIdx.x * 256 + threadIdx.x;   // 0 .. 65535
  const int s = tid & 127;
  float g = ws[WS_PART + tid];
  g = fmaxf(g, ws[WS_PART + 65536 + tid]);
  g = fmaxf(g, ws[WS_PART + 131072 + tid]);
  g = fmaxf(g, ws[WS_PART + 196608 + tid]);
  const float d2 = fmaf(-2.f, g, ws[WS_S2C + s]);
  out[tid] = sqrtf(fmaxf(d2, 0.f));
}

extern "C" void kernel_launch(void* const* d_in, const int* in_sizes, int n_in,
                              void* d_out, int out_size, void* d_ws, size_t ws_size,
                              hipStream_t stream) {
  const float* x  = (const float*)d_in[0];
  const float* sh = (const float*)d_in[1];
  float* out = (float*)d_out;
  float* ws = (float*)d_ws;
  prep_kernel<<<dim3(SS), dim3(64), 0, stream>>>(sh, ws);
  shapelet_main<<<dim3(BB * 4), dim3(256), 0, stream>>>(x, ws);
  combine_kernel<<<dim3(256), dim3(256), 0, stream>>>(ws, out);
}

// Round 10
// 69.886 us; speedup vs baseline: 1.1413x; 1.1413x over previous
//
#include <hip/hip_runtime.h>
#include <hip/hip_bf16.h>

#define BB 512
#define TT 2048
#define SS 128
#define LL 64
#define PP (TT - LL + 1)   // 1985

#define XF_N  2128                // staged fp32 x (zero-padded past 2048)
#define XCP_W 530                 // 8B words per shifted copy; (2*530)%32==4 ->
                                  // copies start 4 banks apart => reads tile 32 banks
#define SH_ROW_SHORTS 72          // 64 data + 8 pad shorts (row stride 144 B)

typedef __attribute__((ext_vector_type(8))) short    short8;
typedef __attribute__((ext_vector_type(4))) float    float4v;
typedef __attribute__((ext_vector_type(4))) unsigned uint4v;

__device__ __forceinline__ unsigned f2bf1(float f) {
  union { float f; unsigned u; } v; v.f = f;
  return (v.u + 0x7FFFu + ((v.u >> 16) & 1u)) >> 16;   // RNE fp32->bf16
}

// ---- single fused kernel: 1 block (512 thr, 8 waves) per sample ----
// wave w: shalf = w&1 (64 shapelets), pq = w>>1 (512 windows, 16 tile-pairs).
// d2 = c0[p] + s2c[s] - 2*cross(x, centered_s); C-init = -c0/2;
// g = max_p(cross - c0/2); out = sqrt(s2c - 2g), s2c = raw sum(s^2).
__global__ __launch_bounds__(512)
void shapelet_fused(const float* __restrict__ x, const float* __restrict__ shg,
                    float* __restrict__ out) {
  __shared__ __align__(16) float xf[XF_N];
  __shared__ __align__(16) unsigned long long xcp[8][XCP_W];
  __shared__ float c0h[2048];
  __shared__ __align__(16) short shb[SS * SH_ROW_SHORTS];
  __shared__ float s2cl[SS];
  __shared__ float wred[8 * 64];

  const int t = threadIdx.x;
  const int b = blockIdx.x;
  const int lane = t & 63, wave = t >> 6;
  const int n = lane & 15, q = lane >> 4;
  const int shalf = wave & 1, pq = wave >> 1;

  // ---- stage x[b] (8 KB) into LDS, zero-pad to XF_N ----
  for (int idx = t; idx < XF_N / 4; idx += 512) {
    const int g0 = 4 * idx;
    float4v v = {0.f, 0.f, 0.f, 0.f};
    if (g0 + 3 < TT) v = *(const float4v*)(x + (size_t)b * TT + g0);
    *(float4v*)(xf + 4 * idx) = v;
  }

  // ---- shapelet prep (redundant per block; 32 KB, L2-resident) ----
  // thread t: row s = t>>2, quarter part = t&3 (16 floats)
  {
    const int s = t >> 2, part = t & 3;
    const float4v* sp = (const float4v*)(shg + s * LL + part * 16);
    float4v r0 = sp[0], r1 = sp[1], r2 = sp[2], r3 = sp[3];
    float sum = 0.f, sq = 0.f;
    #pragma unroll
    for (int k = 0; k < 4; ++k) {
      const float4v rv = (k == 0) ? r0 : (k == 1) ? r1 : (k == 2) ? r2 : r3;
      sum += (rv[0] + rv[1]) + (rv[2] + rv[3]);
      sq = fmaf(rv[0], rv[0], sq); sq = fmaf(rv[1], rv[1], sq);
      sq = fmaf(rv[2], rv[2], sq); sq = fmaf(rv[3], rv[3], sq);
    }
    sum += __shfl_xor(sum, 1); sum += __shfl_xor(sum, 2);
    sq  += __shfl_xor(sq, 1);  sq  += __shfl_xor(sq, 2);
    const float mean = sum * (1.f / 64.f);

    unsigned pk[8];
    #pragma unroll
    for (int k = 0; k < 4; ++k) {
      const float4v rv = (k == 0) ? r0 : (k == 1) ? r1 : (k == 2) ? r2 : r3;
      pk[2 * k]     = f2bf1(rv[0] - mean) | (f2bf1(rv[1] - mean) << 16);
      pk[2 * k + 1] = f2bf1(rv[2] - mean) | (f2bf1(rv[3] - mean) << 16);
    }
    unsigned* shbw = (unsigned*)shb;
    const int dw = s * (SH_ROW_SHORTS / 2) + part * 8;   // 16B aligned
    uint4v w0v = {pk[0], pk[1], pk[2], pk[3]};
    uint4v w1v = {pk[4], pk[5], pk[6], pk[7]};
    *(uint4v*)(shbw + dw) = w0v;
    *(uint4v*)(shbw + dw + 4) = w1v;
    if (part == 0) s2cl[s] = sq;      // s2c = raw sum of squares
  }

  __syncthreads();

  // ---- B fragments from LDS shapelets ----
  short8 bf[2][4];
  #pragma unroll
  for (int st = 0; st < 4; ++st) {
    const int row = shalf * 64 + st * 16 + n;
    bf[0][st] = *(const short8*)(shb + row * SH_ROW_SHORTS + q * 8);
    bf[1][st] = *(const short8*)(shb + row * SH_ROW_SHORTS + 32 + q * 8);
  }

  // ---- build 8 element-shifted bf16 copies of xf ----
  for (int w = t; w < XCP_W; w += 512) {
    const float4v* xf4 = (const float4v*)xf;
    float4v A = xf4[w], Bv = xf4[w + 1], Cv = xf4[w + 2];
    unsigned bfx[11];
    #pragma unroll
    for (int k = 0; k < 4; ++k) bfx[k] = f2bf1(A[k]);
    #pragma unroll
    for (int k = 0; k < 4; ++k) bfx[4 + k] = f2bf1(Bv[k]);
    #pragma unroll
    for (int k = 0; k < 3; ++k) bfx[8 + k] = f2bf1(Cv[k]);
    #pragma unroll
    for (int c = 0; c < 8; ++c) {
      unsigned long long pkw =
          (unsigned long long)bfx[c] |
          ((unsigned long long)bfx[c + 1] << 16) |
          ((unsigned long long)bfx[c + 2] << 32) |
          ((unsigned long long)bfx[c + 3] << 48);
      xcp[c][w] = pkw;
    }
  }

  // ---- window stats: thread t -> windows 4t..4t+3 (rolling, capped unroll) ----
  {
    const float4v* xf4 = (const float4v*)xf;
    float S = 0.f, Q = 0.f;
    float4v v0 = xf4[t];
    float4v vcur = v0;
    #pragma unroll 4
    for (int ch = 0; ch < 16; ++ch) {
      S += (vcur[0] + vcur[1]) + (vcur[2] + vcur[3]);
      Q = fmaf(vcur[0], vcur[0], Q); Q = fmaf(vcur[1], vcur[1], Q);
      Q = fmaf(vcur[2], vcur[2], Q); Q = fmaf(vcur[3], vcur[3], Q);
      vcur = xf4[t + ch + 1];           // after loop: vcur = xf4[t+16]
    }
    const float4v vN = vcur;
    const int p0s = 4 * t;
    #pragma unroll
    for (int r = 0; r < 4; ++r) {
      const bool valid = (p0s + r) < PP;
      const float c0 = Q - S * S * (1.f / 64.f);
      c0h[p0s + r] = valid ? (-0.5f * c0) : -INFINITY;
      if (r < 3) {
        const float vin = vN[r], vout = v0[r];
        S += vin - vout;
        Q += fmaf(vin, vin, -vout * vout);
      }
    }
  }

  __syncthreads();

  // ---- main MFMA loop: branchless rolling A-ring, 2 tiles per iter ----
  // #pragma unroll 1: keep live ranges short -> VGPR <= 128 -> 4 waves/SIMD.
  const int cc = n & 7;
  const int lw = 2 * q + 2 * (n >> 3);          // even => aligned ds_read_b128
  const unsigned long long* xc = &xcp[cc][0];
  const int base = pq * 512;
  const int w0 = (base >> 2) + lw;

  float rmax[4];
  #pragma unroll
  for (int st = 0; st < 4; ++st) rmax[st] = -INFINITY;

  short8 h0 = *(const short8*)&xc[w0];          // frag(base,    kb0)
  short8 h1 = *(const short8*)&xc[w0 + 4];      // frag(base+16, kb0)

  #pragma unroll 1
  for (int mt2 = 0; mt2 < 16; ++mt2) {
    const int wb = w0 + 8 * mt2;
    const short8 l0 = *(const short8*)&xc[wb + 8];    // frag(p0,    kb1)
    const short8 l1 = *(const short8*)&xc[wb + 12];   // frag(p0+16, kb1)
    const int pA = base + 32 * mt2 + 4 * q;
    const float4v c0A = *(const float4v*)&c0h[pA];
    const float4v c0B = *(const float4v*)&c0h[pA + 16];

    #pragma unroll
    for (int st = 0; st < 4; ++st) {
      float4v accA = __builtin_amdgcn_mfma_f32_16x16x32_bf16(h0, bf[0][st], c0A, 0, 0, 0);
      float4v accB = __builtin_amdgcn_mfma_f32_16x16x32_bf16(h1, bf[0][st], c0B, 0, 0, 0);
      accA = __builtin_amdgcn_mfma_f32_16x16x32_bf16(l0, bf[1][st], accA, 0, 0, 0);
      accB = __builtin_amdgcn_mfma_f32_16x16x32_bf16(l1, bf[1][st], accB, 0, 0, 0);
      const float mA = fmaxf(fmaxf(accA[0], accA[1]), fmaxf(accA[2], accA[3]));
      const float mB = fmaxf(fmaxf(accB[0], accB[1]), fmaxf(accB[2], accB[3]));
      rmax[st] = fmaxf(rmax[st], fmaxf(mA, mB));
    }
    h0 = l0;      // frag(p0, kb1) == frag(p0+32, kb0)
    h1 = l1;
  }

  // ---- reduce: across q (shfl), across 4 pq-waves (LDS), write out ----
  #pragma unroll
  for (int st = 0; st < 4; ++st) {
    float v = rmax[st];
    v = fmaxf(v, __shfl_xor(v, 16));
    v = fmaxf(v, __shfl_xor(v, 32));
    if (q == 0) wred[wave * 64 + st * 16 + n] = v;
  }
  __syncthreads();

  if (t < SS) {
    const int g = t >> 6, k = t & 63;           // s = g*64 + k
    const float v = fmaxf(fmaxf(wred[(g) * 64 + k],     wred[(2 + g) * 64 + k]),
                          fmaxf(wred[(4 + g) * 64 + k], wred[(6 + g) * 64 + k]));
    const float d2 = fmaf(-2.f, v, s2cl[t]);
    out[(size_t)b * SS + t] = sqrtf(fmaxf(d2, 0.f));
  }
}

extern "C" void kernel_launch(void* const* d_in, const int* in_sizes, int n_in,
                              void* d_out, int out_size, void* d_ws, size_t ws_size,
                              hipStream_t stream) {
  const float* x  = (const float*)d_in[0];
  const float* sh = (const float*)d_in[1];
  float* out = (float*)d_out;
  shapelet_fused<<<dim3(BB), dim3(512), 0, stream>>>(x, sh, out);
}

// Round 11
// 69.858 us; speedup vs baseline: 1.1418x; 1.0004x over previous
//
#include <hip/hip_runtime.h>
#include <hip/hip_bf16.h>

#define BB 512
#define TT 2048
#define SS 128
#define LL 64
#define PP (TT - LL + 1)   // 1985

#define XF_N  2128                // staged fp32 x (zero-padded past 2048)
#define XCP_W 530                 // 8B words per shifted copy; (2*530)%32==4 ->
                                  // copies start 4 banks apart => reads tile 32 banks
#define SH_ROW_SHORTS 72          // 64 data + 8 pad shorts (row stride 144 B)

typedef __attribute__((ext_vector_type(8))) short    short8;
typedef __attribute__((ext_vector_type(4))) float    float4v;
typedef __attribute__((ext_vector_type(4))) unsigned uint4v;

__device__ __forceinline__ unsigned f2bf1(float f) {
  union { float f; unsigned u; } v; v.f = f;
  return (v.u + 0x7FFFu + ((v.u >> 16) & 1u)) >> 16;   // RNE fp32->bf16
}

// ---- single fused kernel: 1 block (512 thr, 8 waves) per sample ----
// wave w: shalf = w&1 (64 shapelets), pq = w>>1 (512 windows, 32 tiles).
// d2 = c0[p] + s2c[s] - 2*cross(x, centered_s); C-init = -c0/2;
// g = max_p(cross - c0/2); out = sqrt(s2c - 2g), s2c = raw sum(s^2).
// Main loop: ONE 16-p tile/iter to keep VGPR <= 128 (2 blocks/CU resident).
__global__ __launch_bounds__(512)
void shapelet_fused(const float* __restrict__ x, const float* __restrict__ shg,
                    float* __restrict__ out) {
  __shared__ __align__(16) float xf[XF_N];
  __shared__ __align__(16) unsigned long long xcp[8][XCP_W];
  __shared__ float c0h[2048];
  __shared__ __align__(16) short shb[SS * SH_ROW_SHORTS];
  __shared__ float s2cl[SS];
  __shared__ float wred[8 * 64];

  const int t = threadIdx.x;
  const int b = blockIdx.x;
  const int lane = t & 63, wave = t >> 6;
  const int n = lane & 15, q = lane >> 4;
  const int shalf = wave & 1, pq = wave >> 1;

  // ---- stage x[b] (8 KB) into LDS, zero-pad to XF_N ----
  for (int idx = t; idx < XF_N / 4; idx += 512) {
    const int g0 = 4 * idx;
    float4v v = {0.f, 0.f, 0.f, 0.f};
    if (g0 + 3 < TT) v = *(const float4v*)(x + (size_t)b * TT + g0);
    *(float4v*)(xf + 4 * idx) = v;
  }

  // ---- shapelet prep (redundant per block; 32 KB, L2-resident) ----
  // thread t: row s = t>>2, quarter part = t&3 (16 floats)
  {
    const int s = t >> 2, part = t & 3;
    const float4v* sp = (const float4v*)(shg + s * LL + part * 16);
    float4v r0 = sp[0], r1 = sp[1], r2 = sp[2], r3 = sp[3];
    float sum = 0.f, sq = 0.f;
    #pragma unroll
    for (int k = 0; k < 4; ++k) {
      const float4v rv = (k == 0) ? r0 : (k == 1) ? r1 : (k == 2) ? r2 : r3;
      sum += (rv[0] + rv[1]) + (rv[2] + rv[3]);
      sq = fmaf(rv[0], rv[0], sq); sq = fmaf(rv[1], rv[1], sq);
      sq = fmaf(rv[2], rv[2], sq); sq = fmaf(rv[3], rv[3], sq);
    }
    sum += __shfl_xor(sum, 1); sum += __shfl_xor(sum, 2);
    sq  += __shfl_xor(sq, 1);  sq  += __shfl_xor(sq, 2);
    const float mean = sum * (1.f / 64.f);

    unsigned pk[8];
    #pragma unroll
    for (int k = 0; k < 4; ++k) {
      const float4v rv = (k == 0) ? r0 : (k == 1) ? r1 : (k == 2) ? r2 : r3;
      pk[2 * k]     = f2bf1(rv[0] - mean) | (f2bf1(rv[1] - mean) << 16);
      pk[2 * k + 1] = f2bf1(rv[2] - mean) | (f2bf1(rv[3] - mean) << 16);
    }
    unsigned* shbw = (unsigned*)shb;
    const int dw = s * (SH_ROW_SHORTS / 2) + part * 8;   // 16B aligned
    uint4v w0v = {pk[0], pk[1], pk[2], pk[3]};
    uint4v w1v = {pk[4], pk[5], pk[6], pk[7]};
    *(uint4v*)(shbw + dw) = w0v;
    *(uint4v*)(shbw + dw + 4) = w1v;
    if (part == 0) s2cl[s] = sq;      // s2c = raw sum of squares
  }

  __syncthreads();

  // ---- B fragments from LDS shapelets ----
  short8 bf[2][4];
  #pragma unroll
  for (int st = 0; st < 4; ++st) {
    const int row = shalf * 64 + st * 16 + n;
    bf[0][st] = *(const short8*)(shb + row * SH_ROW_SHORTS + q * 8);
    bf[1][st] = *(const short8*)(shb + row * SH_ROW_SHORTS + 32 + q * 8);
  }

  // ---- build 8 element-shifted bf16 copies of xf ----
  for (int w = t; w < XCP_W; w += 512) {
    const float4v* xf4 = (const float4v*)xf;
    float4v A = xf4[w], Bv = xf4[w + 1], Cv = xf4[w + 2];
    unsigned bfx[11];
    #pragma unroll
    for (int k = 0; k < 4; ++k) bfx[k] = f2bf1(A[k]);
    #pragma unroll
    for (int k = 0; k < 4; ++k) bfx[4 + k] = f2bf1(Bv[k]);
    #pragma unroll
    for (int k = 0; k < 3; ++k) bfx[8 + k] = f2bf1(Cv[k]);
    #pragma unroll
    for (int c = 0; c < 8; ++c) {
      unsigned long long pkw =
          (unsigned long long)bfx[c] |
          ((unsigned long long)bfx[c + 1] << 16) |
          ((unsigned long long)bfx[c + 2] << 32) |
          ((unsigned long long)bfx[c + 3] << 48);
      xcp[c][w] = pkw;
    }
  }

  // ---- window stats: thread t -> windows 4t..4t+3 (rolling, capped unroll) ----
  {
    const float4v* xf4 = (const float4v*)xf;
    float S = 0.f, Q = 0.f;
    float4v v0 = xf4[t];
    float4v vcur = v0;
    #pragma unroll 4
    for (int ch = 0; ch < 16; ++ch) {
      S += (vcur[0] + vcur[1]) + (vcur[2] + vcur[3]);
      Q = fmaf(vcur[0], vcur[0], Q); Q = fmaf(vcur[1], vcur[1], Q);
      Q = fmaf(vcur[2], vcur[2], Q); Q = fmaf(vcur[3], vcur[3], Q);
      vcur = xf4[t + ch + 1];           // after loop: vcur = xf4[t+16]
    }
    const float4v vN = vcur;
    const int p0s = 4 * t;
    #pragma unroll
    for (int r = 0; r < 4; ++r) {
      const bool valid = (p0s + r) < PP;
      const float c0 = Q - S * S * (1.f / 64.f);
      c0h[p0s + r] = valid ? (-0.5f * c0) : -INFINITY;
      if (r < 3) {
        const float vin = vN[r], vout = v0[r];
        S += vin - vout;
        Q += fmaf(vin, vin, -vout * vout);
      }
    }
  }

  __syncthreads();

  // ---- main MFMA loop: single 16-p tile per iter, rolling 2-deep A-ring ----
  // frag(p0, kb1) == frag(p0+32, kb0): 1 new A-read + 1 c0-read per tile.
  const int cc = n & 7;
  const int lw = 2 * q + 2 * (n >> 3);          // even => aligned ds_read_b128
  const unsigned long long* xc = &xcp[cc][0];
  const int base = pq * 512;
  const int w0 = (base >> 2) + lw;

  float rmax[4];
  #pragma unroll
  for (int st = 0; st < 4; ++st) rmax[st] = -INFINITY;

  short8 h0 = *(const short8*)&xc[w0];          // frag(base,    kb0)
  short8 h1 = *(const short8*)&xc[w0 + 4];      // frag(base+16, kb0)

  #pragma unroll 2
  for (int mt = 0; mt < 32; ++mt) {
    const short8 l = *(const short8*)&xc[w0 + 4 * mt + 8];   // frag(p0, kb1)
    const float4v c0v = *(const float4v*)&c0h[base + 16 * mt + 4 * q];

    #pragma unroll
    for (int st = 0; st < 4; ++st) {
      float4v acc = __builtin_amdgcn_mfma_f32_16x16x32_bf16(h0, bf[0][st], c0v, 0, 0, 0);
      acc = __builtin_amdgcn_mfma_f32_16x16x32_bf16(l, bf[1][st], acc, 0, 0, 0);
      const float m01 = fmaxf(acc[0], acc[1]);
      const float m23 = fmaxf(acc[2], acc[3]);
      rmax[st] = fmaxf(rmax[st], fmaxf(m01, m23));
    }
    h0 = h1;          // frag(p0, kb1) == frag(p0+32, kb0)
    h1 = l;
  }

  // ---- reduce: across q (shfl), across 4 pq-waves (LDS), write out ----
  #pragma unroll
  for (int st = 0; st < 4; ++st) {
    float v = rmax[st];
    v = fmaxf(v, __shfl_xor(v, 16));
    v = fmaxf(v, __shfl_xor(v, 32));
    if (q == 0) wred[wave * 64 + st * 16 + n] = v;
  }
  __syncthreads();

  if (t < SS) {
    const int g = t >> 6, k = t & 63;           // s = g*64 + k
    const float v = fmaxf(fmaxf(wred[(g) * 64 + k],     wred[(2 + g) * 64 + k]),
                          fmaxf(wred[(4 + g) * 64 + k], wred[(6 + g) * 64 + k]));
    const float d2 = fmaf(-2.f, v, s2cl[t]);
    out[(size_t)b * SS + t] = sqrtf(fmaxf(d2, 0.f));
  }
}

extern "C" void kernel_launch(void* const* d_in, const int* in_sizes, int n_in,
                              void* d_out, int out_size, void* d_ws, size_t ws_size,
                              hipStream_t stream) {
  const float* x  = (const float*)d_in[0];
  const float* sh = (const float*)d_in[1];
  float* out = (float*)d_out;
  shapelet_fused<<<dim3(BB), dim3(512), 0, stream>>>(x, sh, out);
}